// Round 7
// baseline (231.214 us; speedup 1.0000x reference)
//
#include <hip/hip_runtime.h>
#include <math.h>

#define BB 8192
#define KK 32
#define DD 129      // hyperboloid dim = D + 1
#define VV 2048
#define NN 33       // K + 1
#define TOPK 10
#define WPB 4       // waves per block in lr_rank

__device__ __forceinline__ float fast_rcp(float x) { return __builtin_amdgcn_rcpf(x); }

// ================= Kernel 1: pure streaming of Lorentz inner products ======
// block = 1024 threads = 16 waves, one block per batch.
// wave w computes rows w and 16+w; wave 0 additionally row 32.
// Stores x = max(-inner, 1+1e-7)  (acosh deferred to lr_rank).
__global__ __launch_bounds__(1024) void lr_dist(
    const float* __restrict__ anchor,
    const float* __restrict__ positive,
    const float* __restrict__ neg,
    float* __restrict__ xout)          // [BB][NN]
{
    const int b    = blockIdx.x;
    const int wave = threadIdx.x >> 6;
    const int lane = threadIdx.x & 63;

    const float* ab = anchor   + (size_t)b * DD;
    const float* pb = positive + (size_t)b * DD;
    const float* nb = neg      + (size_t)b * (KK * DD);

    const int row0 = wave;            // 0..15
    const int row1 = wave + 16;       // 16..31
    const float* r0 = (row0 == 0) ? pb : (nb + (size_t)(row0 - 1) * DD);
    const float* r1 = nb + (size_t)(row1 - 1) * DD;

    // issue all loads up front (independent)
    const float a_lo = ab[lane];
    const float a_hi = ab[64 + lane];
    const float a128 = ab[128];
    const float v0_lo = r0[lane], v0_hi = r0[64 + lane], v0_128 = r0[128];
    const float v1_lo = r1[lane], v1_hi = r1[64 + lane], v1_128 = r1[128];

    // row0 dot
    {
        float s = fmaf(a_lo, v0_lo, a_hi * v0_hi);
        #pragma unroll
        for (int off = 32; off > 0; off >>= 1) s += __shfl_xor(s, off, 64);
        if (lane == 0) {
            float full = s + a128 * v0_128;                    // sum_{0..128}
            float x = fmaxf(fmaf(2.0f * a_lo, v0_lo, -full), 1.0f + 1e-07f);
            xout[(size_t)b * NN + row0] = x;
        }
    }
    // row1 dot
    {
        float s = fmaf(a_lo, v1_lo, a_hi * v1_hi);
        #pragma unroll
        for (int off = 32; off > 0; off >>= 1) s += __shfl_xor(s, off, 64);
        if (lane == 0) {
            float full = s + a128 * v1_128;
            float x = fmaxf(fmaf(2.0f * a_lo, v1_lo, -full), 1.0f + 1e-07f);
            xout[(size_t)b * NN + row1] = x;
        }
    }
    // row 32 (wave 0 only; wave-uniform branch)
    if (wave == 0) {
        const float* r2 = nb + (size_t)(KK - 1) * DD;
        float v2_lo = r2[lane], v2_hi = r2[64 + lane], v2_128 = r2[128];
        float s = fmaf(a_lo, v2_lo, a_hi * v2_hi);
        #pragma unroll
        for (int off = 32; off > 0; off >>= 1) s += __shfl_xor(s, off, 64);
        if (lane == 0) {
            float full = s + a128 * v2_128;
            float x = fmaxf(fmaf(2.0f * a_lo, v2_lo, -full), 1.0f + 1e-07f);
            xout[(size_t)b * NN + KK] = x;
        }
    }
}

// ================= Kernel 2: per-batch rank / NDCG / pair sum ==============
// one wave per batch; per-wave private LDS slices; no barriers.
__global__ __launch_bounds__(256) void lr_rank(
    const float* __restrict__ xin,     // [BB][NN] clamped -inner
    const float* __restrict__ tree,
    const int* __restrict__ a_idx,
    const int* __restrict__ p_idx,
    const int* __restrict__ n_idx,
    float* __restrict__ partial)
{
    __shared__ float  st_[WPB][NN];
    __shared__ float  sd_[WPB][NN];
    __shared__ float4 sitem[WPB][NN];

    const int t    = threadIdx.x;
    const int wave = t >> 6;
    const int lane = t & 63;
    const int b    = blockIdx.x * WPB + wave;

    // tree gather (lanes >=33 clamped dup, discarded)
    const int ai  = a_idx[b];
    const int col = (lane == 0) ? p_idx[b]
                                : n_idx[(size_t)b * KK + ((lane < NN ? lane : KK) - 1)];
    const float tg = tree[(size_t)ai * VV + col];
    if (lane < NN) st_[wave][lane] = tg;

    // dense acosh on precomputed x
    float dlane = 0.0f;
    if (lane < NN) {
        float x = xin[(size_t)b * NN + lane];
        dlane = __logf(x + sqrtf(x * x - 1.0f));       // acosh(x)
        sd_[wave][lane] = dlane;
    }

    // rel + stable rank -> disc
    if (lane < NN) {
        float maxt = st_[wave][0];
        #pragma unroll
        for (int j = 1; j < NN; ++j) maxt = fmaxf(maxt, st_[wave][j]);
        float rel = (maxt - tg + 1e-06f) * fast_rcp(maxt + 1e-06f);

        int cnt = 0;
        #pragma unroll
        for (int j = 0; j < NN; ++j) {
            float dj = sd_[wave][j];
            cnt += (int)((dj < dlane) | ((dj == dlane) & (j < lane)));
        }
        float disc = (cnt + 1 <= TOPK) ? fast_rcp(log2f((float)(cnt + 2))) : 0.0f;
        sitem[wave][lane] = make_float4(dlane, rel, disc, 0.0f);
    }

    // IDCG (stable descending position) -> inv broadcast in regs
    float c = 0.0f;
    if (lane < NN) {
        float ri = sitem[wave][lane].y;
        int pos = 0;
        #pragma unroll
        for (int j = 0; j < NN; ++j) {
            float rj = sitem[wave][j].y;
            pos += (int)((rj > ri) | ((rj == ri) & (j < lane)));
        }
        if (pos < TOPK) c = ri * fast_rcp(log2f((float)(pos + 2)));
    }
    #pragma unroll
    for (int off = 32; off > 0; off >>= 1) c += __shfl_xor(c, off, 64);
    const float inv = (c > 0.0f) ? fast_rcp(c) : 0.0f;

    // pair sum over i<j (symmetric term: full sum = 2 * this)
    float acc = 0.0f;
    #pragma unroll
    for (int it = 0; it < 9; ++it) {
        int p = it * 64 + lane;                  // 0..575
        float vmask = (p < 528) ? 1.0f : 0.0f;
        int pc = (p < 528) ? p : 527;
        int j = (int)((1.0f + sqrtf((float)(8 * pc + 1))) * 0.5f);
        int tj = (j * (j - 1)) >> 1;
        if (tj > pc) { --j; tj = (j * (j - 1)) >> 1; }
        int i = pc - tj;
        float4 Ii = sitem[wave][i];
        float4 Ij = sitem[wave][j];
        float dd    = Ij.x - Ii.x;               // d[j] - d[i]
        float drel  = Ii.y - Ij.y;
        float ddisc = Ii.z - Ij.z;
        float t1  = drel * fabsf(ddisc) * (inv * vmask);   // S * delta (masked)
        float e   = __expf(-dd);
        float num = (drel >= 0.0f) ? 1.0f : e;
        acc = fmaf(t1 * num * fast_rcp(1.0f + e), -dd, acc);
    }
    #pragma unroll
    for (int off = 32; off > 0; off >>= 1) acc += __shfl_xor(acc, off, 64);
    if (lane == 0) partial[b] = acc;             // == 0.5 * full pair sum
}

__global__ __launch_bounds__(256) void lr_reduce(
    const float* __restrict__ partial, float* __restrict__ out)
{
    __shared__ float swave[4];
    const float4* p4 = (const float4*)partial;
    float acc = 0.0f;
    #pragma unroll
    for (int c = 0; c < (BB / 4) / 256; ++c) {
        float4 v = p4[c * 256 + threadIdx.x];
        acc += (v.x + v.y) + (v.z + v.w);
    }
    #pragma unroll
    for (int off = 32; off > 0; off >>= 1) acc += __shfl_xor(acc, off, 64);
    if ((threadIdx.x & 63) == 0) swave[threadIdx.x >> 6] = acc;
    __syncthreads();
    if (threadIdx.x == 0)
        out[0] = (swave[0] + swave[1] + swave[2] + swave[3]) * (0.15f / (float)BB);
}

extern "C" void kernel_launch(void* const* d_in, const int* in_sizes, int n_in,
                              void* d_out, int out_size, void* d_ws, size_t ws_size,
                              hipStream_t stream)
{
    const float* anchor   = (const float*)d_in[0];
    const float* positive = (const float*)d_in[1];
    const float* neg      = (const float*)d_in[2];
    const float* tree     = (const float*)d_in[3];
    const int*   a_idx    = (const int*)d_in[4];
    const int*   p_idx    = (const int*)d_in[5];
    const int*   n_idx    = (const int*)d_in[6];

    float* xbuf    = (float*)d_ws;                    // BB*NN floats
    float* partial = (float*)d_ws + (size_t)BB * NN;  // BB floats (16B-aligned offset)

    lr_dist<<<BB, 1024, 0, stream>>>(anchor, positive, neg, xbuf);
    lr_rank<<<BB / WPB, 256, 0, stream>>>(xbuf, tree, a_idx, p_idx, n_idx, partial);
    lr_reduce<<<1, 256, 0, stream>>>(partial, (float*)d_out);
}